// Round 2
// baseline (247.667 us; speedup 1.0000x reference)
//
#include <hip/hip_runtime.h>
#include <stdint.h>
#include <stddef.h>

// Problem dims (fixed by reference)
#define BB 8192
#define TT 26
#define VV 23
#define EE 100
#define HH 128
#define LL 64

typedef __attribute__((ext_vector_type(8))) short bf16x8;  // 8 bf16 = 4 VGPRs
typedef __attribute__((ext_vector_type(4))) float f32x4;   // MFMA 16x16 C/D

#define MFMA(a, b, c) __builtin_amdgcn_mfma_f32_16x16x32_bf16((a), (b), (c), 0, 0, 0)

// ---------------- workspace layout (bytes) ----------------
#define OFF_GRUW   0ull                  // GRU Whh B-frags: 24ct*4kc*1024
#define OFF_TBL    98304ull              // one-hot table B-frags: 24ct*1024
#define OFF_LSTMW  122880ull             // LSTM fused W B-frags: 28ct*8kc*1024 (kc0-3=y, kc4-7=h)
#define OFF_OUTW   352256ull             // out_w B-frags: 2ct*4kc*1024
#define OFF_FCZW   360448ull             // fc_z_w B-frags: 8ct*2kc*1024
#define OFF_LBIAS  376832ull             // fused LSTM bias 4*112 fp32
#define OFF_Y      379904ull             // y A-frags: 512 btile * 26 t * 4 kc * 1024B

__device__ __forceinline__ unsigned short f2bf(float f) {
  union { float f; unsigned u; } v; v.f = f;
  unsigned u = v.u;
  return (unsigned short)((u + 0x7FFFu + ((u >> 16) & 1u)) >> 16);  // RNE
}
__device__ __forceinline__ float sigm(float x) { return 1.0f / (1.0f + __expf(-x)); }
__device__ __forceinline__ float tanh_(float x) { return 2.0f / (1.0f + __expf(-2.0f * x)) - 1.0f; }

// =====================================================================
// K0: weight swizzle into MFMA B-frag order. Frag (ct,kc): lane holds
// B[k][n], n = ct*16+(lane&15), k = kc*32 + ((lane>>4)&3)*8 + j.
// =====================================================================
__global__ __launch_bounds__(256) void prep_kernel(
    const float* __restrict__ emb, const float* __restrict__ fc_z_w,
    const float* __restrict__ gru_wih, const float* __restrict__ gru_whh,
    const float* __restrict__ gru_bih,
    const float* __restrict__ lstm_wih, const float* __restrict__ lstm_whh,
    const float* __restrict__ lstm_bih, const float* __restrict__ lstm_bhh,
    const float* __restrict__ out_w,
    char* __restrict__ ws)
{
  int e = blockIdx.x * 256 + threadIdx.x;

  if (e < 49152) {  // GRU Whh (384x128)
    int j = e & 7, lane = (e >> 3) & 63, kc = (e >> 9) & 3, ct = e >> 11;
    int n = ct * 16 + (lane & 15);
    int k = kc * 32 + ((lane >> 4) & 3) * 8 + j;
    *(unsigned short*)(ws + OFF_GRUW + (size_t)e * 2) = f2bf(gru_whh[n * HH + k]);
    return;
  }
  e -= 49152;
  if (e < 12288) {  // one-hot table: emb[k]@gru_wih[n] + bih[n]
    int j = e & 7, lane = (e >> 3) & 63, ct = e >> 9;
    int n = ct * 16 + (lane & 15);
    int k = ((lane >> 4) & 3) * 8 + j;
    float v = 0.0f;
    if (k < VV) {
      float s0 = 0.f, s1 = 0.f, s2 = 0.f, s3 = 0.f;
      const float* ep = emb + k * EE;
      const float* wp = gru_wih + n * EE;
#pragma unroll 5
      for (int m = 0; m < EE; m += 4) {
        s0 += ep[m] * wp[m];     s1 += ep[m + 1] * wp[m + 1];
        s2 += ep[m + 2] * wp[m + 2]; s3 += ep[m + 3] * wp[m + 3];
      }
      v = gru_bih[n] + ((s0 + s1) + (s2 + s3));
    }
    *(unsigned short*)(ws + OFF_TBL + (size_t)e * 2) = f2bf(v);
    return;
  }
  e -= 12288;
  if (e < 114688) {  // LSTM fused W: row=112g+c, K=[y 0..127 | h 0..127]
    int j = e & 7, lane = (e >> 3) & 63, kc = (e >> 9) & 7, ct = e >> 12;
    int row = ct * 16 + (lane & 15);
    int g = row / 112, c = row % 112;
    int q = (lane >> 4) & 3;
    float v = 0.0f;
    if (c < EE) {
      if (kc < 4) {
        int k = kc * 32 + q * 8 + j;
        v = lstm_wih[(g * EE + c) * HH + k];
      } else {
        int k = (kc - 4) * 32 + q * 8 + j;
        if (k < EE) v = lstm_whh[(g * EE + c) * EE + k];
      }
    }
    *(unsigned short*)(ws + OFF_LSTMW + (size_t)e * 2) = f2bf(v);
    return;
  }
  e -= 114688;
  if (e < 4096) {  // out_w (23x100 -> 32x128)
    int j = e & 7, lane = (e >> 3) & 63, kc = (e >> 9) & 3, ct = e >> 11;
    int n = ct * 16 + (lane & 15);
    int k = kc * 32 + ((lane >> 4) & 3) * 8 + j;
    float v = (n < VV && k < EE) ? out_w[n * EE + k] : 0.0f;
    *(unsigned short*)(ws + OFF_OUTW + (size_t)e * 2) = f2bf(v);
    return;
  }
  e -= 4096;
  if (e < 8192) {  // fc_z_w (128x64)
    int j = e & 7, lane = (e >> 3) & 63, kc = (e >> 9) & 1, ct = e >> 10;
    int n = ct * 16 + (lane & 15);
    int k = kc * 32 + ((lane >> 4) & 3) * 8 + j;
    *(unsigned short*)(ws + OFF_FCZW + (size_t)e * 2) = f2bf(fc_z_w[n * LL + k]);
    return;
  }
  e -= 8192;
  if (e < 448) {  // fused LSTM bias
    int g = e / 112, c = e % 112;
    float v = (c < EE) ? (lstm_bih[g * EE + c] + lstm_bhh[g * EE + c]) : 0.0f;
    *(float*)(ws + OFF_LBIAS + (size_t)e * 4) = v;
  }
}

// =====================================================================
// K1: GRU scan. 512 blocks x 512 thr (8 waves), 16 rows/block.
// h double-buffered in LDS directly in A-FRAG layout: frag[kc][lane][8]
// -> ds_read_b128 conflict-free. One-hot/table MFMAs hoisted before the
// h-dependent reads. Exports y_t A-frags to ws.
// =====================================================================
__global__ __launch_bounds__(512, 4) void gru_kernel(
    const float* __restrict__ z, const int* __restrict__ x_in,
    const float* __restrict__ fc_z_b, const float* __restrict__ gru_bhh,
    char* __restrict__ ws)
{
  __shared__ unsigned short hfrag[2][2048];   // 4 kc frags of 1024B each
  __shared__ unsigned char idx_lds[TT * 16];
  const int tid  = threadIdx.x;
  const int wv   = tid >> 6;
  const int lane = tid & 63;
  const int l15  = lane & 15;
  const int q    = (lane >> 4) & 3;
  const int blk  = blockIdx.x;

  for (int i = tid; i < TT * 16; i += 512) {
    int t = i >> 4, r = i & 15;
    idx_lds[i] = (unsigned char)x_in[(blk * 16 + r) * TT + t];
  }

  // stationary weight fragments
  bf16x8 gw[3][4], tw[3];
#pragma unroll
  for (int g = 0; g < 3; g++) {
    int ct = g * 8 + wv;
#pragma unroll
    for (int kc = 0; kc < 4; kc++)
      gw[g][kc] = *(const bf16x8*)(ws + OFF_GRUW + (size_t)(ct * 4 + kc) * 1024 + lane * 16);
    tw[g] = *(const bf16x8*)(ws + OFF_TBL + (size_t)ct * 1024 + lane * 16);
  }
  const int col = wv * 16 + l15;
  const float b_r = gru_bhh[0 * HH + col];
  const float b_z = gru_bhh[1 * HH + col];
  const float b_n = gru_bhh[2 * HH + col];
  // A-frag write coords for this col: entry = wkc*512 + (wq*16+row)*8 + wj
  const int wbase = (col >> 5) * 512 + ((col >> 3) & 3) * 128 + (col & 7);

  // h0 = tanh(z @ fc_z_w^T + fc_z_b) via MFMA
  float h[4];
  {
    bf16x8 fw0 = *(const bf16x8*)(ws + OFF_FCZW + (size_t)(wv * 2 + 0) * 1024 + lane * 16);
    bf16x8 fw1 = *(const bf16x8*)(ws + OFF_FCZW + (size_t)(wv * 2 + 1) * 1024 + lane * 16);
    const float* zp = z + (size_t)(blk * 16 + l15) * LL + q * 8;
    f32x4 z0 = *(const f32x4*)(zp);
    f32x4 z1 = *(const f32x4*)(zp + 4);
    f32x4 z2 = *(const f32x4*)(zp + 32);
    f32x4 z3 = *(const f32x4*)(zp + 36);
    bf16x8 za0, za1;
#pragma unroll
    for (int j = 0; j < 4; j++) {
      za0[j]     = (short)f2bf(z0[j]);
      za0[4 + j] = (short)f2bf(z1[j]);
      za1[j]     = (short)f2bf(z2[j]);
      za1[4 + j] = (short)f2bf(z3[j]);
    }
    float fzb = fc_z_b[col];
    f32x4 acc = {fzb, fzb, fzb, fzb};
    acc = MFMA(za0, fw0, acc);
    acc = MFMA(za1, fw1, acc);
#pragma unroll
    for (int i = 0; i < 4; i++) {
      h[i] = tanh_(acc[i]);
      hfrag[0][wbase + (q * 4 + i) * 8] = f2bf(h[i]);
    }
  }
  __syncthreads();

  int cur = 0;
  for (int t = 0; t < TT; t++) {
    // --- h-independent part first: bias init + one-hot table MFMAs ---
    int iv = idx_lds[t * 16 + l15];
    bf16x8 oh;
#pragma unroll
    for (int j = 0; j < 8; j++)
      oh[j] = (short)((iv == q * 8 + j) ? 0x3F80 : 0);

    f32x4 ar  = {b_r, b_r, b_r, b_r};
    f32x4 az  = {b_z, b_z, b_z, b_z};
    f32x4 ahn = {b_n, b_n, b_n, b_n};
    f32x4 axn = {0.0f, 0.0f, 0.0f, 0.0f};
    ar  = MFMA(oh, tw[0], ar);
    az  = MFMA(oh, tw[1], az);
    axn = MFMA(oh, tw[2], axn);

    // --- h-dependent part: conflict-free b128 A-frag reads ---
    bf16x8 a[4];
#pragma unroll
    for (int kc = 0; kc < 4; kc++)
      a[kc] = *(const bf16x8*)((const char*)hfrag[cur] + kc * 1024 + lane * 16);
#pragma unroll
    for (int kc = 0; kc < 4; kc++) {
      ar  = MFMA(a[kc], gw[0][kc], ar);
      az  = MFMA(a[kc], gw[1][kc], az);
      ahn = MFMA(a[kc], gw[2][kc], ahn);
    }

    int nb = cur ^ 1;
#pragma unroll
    for (int i = 0; i < 4; i++) {
      float r  = sigm(ar[i]);
      float zg = sigm(az[i]);
      float n  = tanh_(axn[i] + r * ahn[i]);
      h[i] = (1.0f - zg) * n + zg * h[i];
      hfrag[nb][wbase + (q * 4 + i) * 8] = f2bf(h[i]);
    }
    __syncthreads();
    // export y_t A-frags (already frag layout -> direct b128 copy)
    if (wv < 4) {
      bf16x8 yv = *(const bf16x8*)((const char*)hfrag[nb] + wv * 1024 + lane * 16);
      *(bf16x8*)(ws + OFF_Y + ((size_t)(blk * TT + t) * 4 + wv) * 1024 + lane * 16) = yv;
    }
    cur = nb;
  }
}

// =====================================================================
// K2: LSTM scan + logits, wave-specialized. 512 blocks x 960 thr
// (15 waves), 16 rows/block. Waves 0-6: y-projection (K=128, no
// recurrence, 1 phase ahead) -> P in LDS (C-layout, coalesced).
// Waves 7-13: recurrent part (K=112->128), acc-init from P, h in
// A-frag-layout dbuf LDS. Wave 14: logits, 2 phases behind.
// 28 phases, one barrier each. <=128 VGPR/wave -> 4 waves/SIMD.
// =====================================================================
__global__ __launch_bounds__(960) void lstm_kernel(
    const float* __restrict__ out_b, char* __restrict__ ws,
    float* __restrict__ out)
{
  __shared__ float Pbuf[2][4 * 7 * 64 * 4];       // 28 KB per buffer
  __shared__ unsigned short hbuf[2][2048];        // 4 KB per buffer (A-frags)
  const int tid  = threadIdx.x;
  const int wv   = tid >> 6;        // 0..14
  const int lane = tid & 63;
  const int l15  = lane & 15;
  const int q    = (lane >> 4) & 3;
  const int blk  = blockIdx.x;      // 0..511

  for (int i = tid; i < 4096; i += 960)
    ((unsigned short*)hbuf)[i] = 0;
  __syncthreads();

  if (wv < 7) {
    // ---------------- y-projection waves ----------------
    bf16x8 lwy[4][4];
#pragma unroll
    for (int g = 0; g < 4; g++)
#pragma unroll
      for (int kc = 0; kc < 4; kc++)
        lwy[g][kc] = *(const bf16x8*)(ws + OFF_LSTMW + (size_t)((g * 7 + wv) * 8 + kc) * 1024 + lane * 16);
    const int col = wv * 16 + l15;
    const float* lb = (const float*)(ws + OFF_LBIAS);
    float b[4];
#pragma unroll
    for (int g = 0; g < 4; g++) b[g] = lb[g * 112 + col];

    bf16x8 ya[4];
#pragma unroll
    for (int kc = 0; kc < 4; kc++)
      ya[kc] = *(const bf16x8*)(ws + OFF_Y + ((size_t)(blk * TT + 0) * 4 + kc) * 1024 + lane * 16);

    for (int p = 0; p < TT + 2; p++) {
      if (p <= TT - 1) {
#pragma unroll
        for (int g = 0; g < 4; g++) {
          f32x4 acc = {b[g], b[g], b[g], b[g]};
#pragma unroll
          for (int kc = 0; kc < 4; kc++)
            acc = MFMA(ya[kc], lwy[g][kc], acc);
          *(f32x4*)&Pbuf[p & 1][((g * 7 + wv) * 64 + lane) * 4] = acc;
        }
        if (p < TT - 1) {
#pragma unroll
          for (int kc = 0; kc < 4; kc++)
            ya[kc] = *(const bf16x8*)(ws + OFF_Y + ((size_t)(blk * TT + p + 1) * 4 + kc) * 1024 + lane * 16);
        }
      }
      __syncthreads();
    }
  } else if (wv < 14) {
    // ---------------- recurrent waves ----------------
    const int tile = wv - 7;
    bf16x8 lwh[4][4];
#pragma unroll
    for (int g = 0; g < 4; g++)
#pragma unroll
      for (int kc = 0; kc < 4; kc++)
        lwh[g][kc] = *(const bf16x8*)(ws + OFF_LSTMW + (size_t)((g * 7 + tile) * 8 + kc + 4) * 1024 + lane * 16);
    const int col = tile * 16 + l15;
    const int wbase = (col >> 5) * 512 + ((col >> 3) & 3) * 128 + (col & 7);
    float c[4] = {0, 0, 0, 0};

    for (int p = 0; p < TT + 2; p++) {
      if (p >= 1 && p <= TT) {
        const int rb = (p - 1) & 1;
        f32x4 ai = *(const f32x4*)&Pbuf[rb][((0 * 7 + tile) * 64 + lane) * 4];
        f32x4 af = *(const f32x4*)&Pbuf[rb][((1 * 7 + tile) * 64 + lane) * 4];
        f32x4 ag = *(const f32x4*)&Pbuf[rb][((2 * 7 + tile) * 64 + lane) * 4];
        f32x4 ao = *(const f32x4*)&Pbuf[rb][((3 * 7 + tile) * 64 + lane) * 4];
        bf16x8 ha[4];
#pragma unroll
        for (int kc = 0; kc < 4; kc++)
          ha[kc] = *(const bf16x8*)((const char*)hbuf[p & 1] + kc * 1024 + lane * 16);
#pragma unroll
        for (int kc = 0; kc < 4; kc++) {
          ai = MFMA(ha[kc], lwh[0][kc], ai);
          af = MFMA(ha[kc], lwh[1][kc], af);
          ag = MFMA(ha[kc], lwh[2][kc], ag);
          ao = MFMA(ha[kc], lwh[3][kc], ao);
        }
#pragma unroll
        for (int i = 0; i < 4; i++) {
          float ii = sigm(ai[i]), ff = sigm(af[i]);
          float gg = tanh_(ag[i]), oo = sigm(ao[i]);
          float cn = ff * c[i] + ii * gg;
          c[i] = cn;
          hbuf[rb][wbase + (q * 4 + i) * 8] = f2bf(oo * tanh_(cn));
        }
      }
      __syncthreads();
    }
  } else {
    // ---------------- logits wave ----------------
    bf16x8 ow[2][4];
#pragma unroll
    for (int ct = 0; ct < 2; ct++)
#pragma unroll
      for (int kc = 0; kc < 4; kc++)
        ow[ct][kc] = *(const bf16x8*)(ws + OFF_OUTW + (size_t)(ct * 4 + kc) * 1024 + lane * 16);
    float ob[2];
#pragma unroll
    for (int ct = 0; ct < 2; ct++) {
      int cv = ct * 16 + l15;
      ob[ct] = (cv < VV) ? out_b[cv] : 0.0f;
    }

    for (int p = 0; p < TT + 2; p++) {
      if (p >= 2) {
        const int t = p - 2;
        bf16x8 ha[4];
#pragma unroll
        for (int kc = 0; kc < 4; kc++)
          ha[kc] = *(const bf16x8*)((const char*)hbuf[p & 1] + kc * 1024 + lane * 16);
#pragma unroll
        for (int ct = 0; ct < 2; ct++) {
          f32x4 acc = {ob[ct], ob[ct], ob[ct], ob[ct]};
#pragma unroll
          for (int kc = 0; kc < 4; kc++)
            acc = MFMA(ha[kc], ow[ct][kc], acc);
          int cv = ct * 16 + l15;
          if (cv < VV) {
#pragma unroll
            for (int i = 0; i < 4; i++) {
              int rowg = blk * 16 + q * 4 + i;
              out[((size_t)rowg * TT + t) * VV + cv] = acc[i];
            }
          }
        }
      }
      __syncthreads();
    }
  }
}

extern "C" void kernel_launch(void* const* d_in, const int* in_sizes, int n_in,
                              void* d_out, int out_size, void* d_ws, size_t ws_size,
                              hipStream_t stream) {
  (void)in_sizes; (void)n_in; (void)out_size; (void)ws_size;
  const float* z        = (const float*)d_in[0];
  const int*   x_in     = (const int*)  d_in[1];
  const float* emb      = (const float*)d_in[2];
  const float* fc_z_w   = (const float*)d_in[3];
  const float* fc_z_b   = (const float*)d_in[4];
  const float* gru_wih  = (const float*)d_in[5];
  const float* gru_whh  = (const float*)d_in[6];
  const float* gru_bih  = (const float*)d_in[7];
  const float* gru_bhh  = (const float*)d_in[8];
  const float* lstm_wih = (const float*)d_in[9];
  const float* lstm_whh = (const float*)d_in[10];
  const float* lstm_bih = (const float*)d_in[11];
  const float* lstm_bhh = (const float*)d_in[12];
  const float* out_w    = (const float*)d_in[13];
  const float* out_b    = (const float*)d_in[14];
  char*  ws  = (char*)d_ws;
  float* out = (float*)d_out;

  prep_kernel<<<738, 256, 0, stream>>>(emb, fc_z_w, gru_wih, gru_whh, gru_bih,
                                       lstm_wih, lstm_whh, lstm_bih, lstm_bhh,
                                       out_w, ws);
  gru_kernel<<<512, 512, 0, stream>>>(z, x_in, fc_z_b, gru_bhh, ws);
  lstm_kernel<<<512, 960, 0, stream>>>(out_b, ws, out);
}

// Round 4
// 190.582 us; speedup vs baseline: 1.2995x; 1.2995x over previous
//
#include <hip/hip_runtime.h>
#include <stdint.h>
#include <stddef.h>

// Problem dims (fixed by reference)
#define BB 8192
#define TT 26
#define VV 23
#define EE 100
#define HH 128
#define LL 64

typedef __attribute__((ext_vector_type(8))) short bf16x8;  // 8 bf16 = 4 VGPRs
typedef __attribute__((ext_vector_type(4))) float f32x4;   // MFMA 16x16 C/D

#define MFMA(a, b, c) __builtin_amdgcn_mfma_f32_16x16x32_bf16((a), (b), (c), 0, 0, 0)

// ---------------- workspace layout (bytes) ----------------
#define OFF_GRUW   0ull                  // GRU Whh B-frags: 24ct*4kc*1024
#define OFF_TBL    98304ull              // one-hot table B-frags: 24ct*1024
#define OFF_LSTMW  122880ull             // LSTM fused W B-frags: 28ct*8kc*1024 (kc0-3=y, kc4-7=h)
#define OFF_OUTW   352256ull             // out_w B-frags: 2ct*4kc*1024
#define OFF_FCZW   360448ull             // fc_z_w B-frags: 8ct*2kc*1024
#define OFF_LBIAS  376832ull             // fused LSTM bias 4*112 fp32
#define OFF_Y      379904ull             // y A-frags: 512 btile * 26 t * 4 kc * 1024B

// Exact RNE (prep only — weights are rounded once, keep them accurate)
__device__ __forceinline__ unsigned short f2bf(float f) {
  union { float f; unsigned u; } v; v.f = f;
  unsigned u = v.u;
  return (unsigned short)((u + 0x7FFFu + ((u >> 16) & 1u)) >> 16);  // RNE
}
// Fast convert for in-loop state (round-half-up; differs from RNE only on
// exact ties, <=1 bf16 ulp): 2 VALU insts vs 5.
__device__ __forceinline__ unsigned short f2bf_fast(float f) {
  union { float f; unsigned u; } v; v.f = f;
  return (unsigned short)((v.u + 0x8000u) >> 16);
}
// Division-free gate math: v_exp_f32 + v_rcp_f32, no IEEE-div fixup chains.
#define LOG2E 1.4426950408889634f
__device__ __forceinline__ float sigm(float x) {
  return __builtin_amdgcn_rcpf(1.0f + __builtin_amdgcn_exp2f(-x * LOG2E));
}
__device__ __forceinline__ float tanh_(float x) {
  // tanh(x) = 1 - 2/(1+e^{2x})
  return __builtin_fmaf(-2.0f,
      __builtin_amdgcn_rcpf(1.0f + __builtin_amdgcn_exp2f(x * (2.0f * LOG2E))), 1.0f);
}

// =====================================================================
// K0: weight swizzle into MFMA B-frag order. Frag (ct,kc): lane holds
// B[k][n], n = ct*16+(lane&15), k = kc*32 + ((lane>>4)&3)*8 + j.
// =====================================================================
__global__ __launch_bounds__(256) void prep_kernel(
    const float* __restrict__ emb, const float* __restrict__ fc_z_w,
    const float* __restrict__ gru_wih, const float* __restrict__ gru_whh,
    const float* __restrict__ gru_bih,
    const float* __restrict__ lstm_wih, const float* __restrict__ lstm_whh,
    const float* __restrict__ lstm_bih, const float* __restrict__ lstm_bhh,
    const float* __restrict__ out_w,
    char* __restrict__ ws)
{
  int e = blockIdx.x * 256 + threadIdx.x;

  if (e < 49152) {  // GRU Whh (384x128)
    int j = e & 7, lane = (e >> 3) & 63, kc = (e >> 9) & 3, ct = e >> 11;
    int n = ct * 16 + (lane & 15);
    int k = kc * 32 + ((lane >> 4) & 3) * 8 + j;
    *(unsigned short*)(ws + OFF_GRUW + (size_t)e * 2) = f2bf(gru_whh[n * HH + k]);
    return;
  }
  e -= 49152;
  if (e < 12288) {  // one-hot table: emb[k]@gru_wih[n] + bih[n]
    int j = e & 7, lane = (e >> 3) & 63, ct = e >> 9;
    int n = ct * 16 + (lane & 15);
    int k = ((lane >> 4) & 3) * 8 + j;
    float v = 0.0f;
    if (k < VV) {
      float s0 = 0.f, s1 = 0.f, s2 = 0.f, s3 = 0.f;
      const float* ep = emb + k * EE;
      const float* wp = gru_wih + n * EE;
#pragma unroll 5
      for (int m = 0; m < EE; m += 4) {
        s0 += ep[m] * wp[m];     s1 += ep[m + 1] * wp[m + 1];
        s2 += ep[m + 2] * wp[m + 2]; s3 += ep[m + 3] * wp[m + 3];
      }
      v = gru_bih[n] + ((s0 + s1) + (s2 + s3));
    }
    *(unsigned short*)(ws + OFF_TBL + (size_t)e * 2) = f2bf(v);
    return;
  }
  e -= 12288;
  if (e < 114688) {  // LSTM fused W: row=112g+c, K=[y 0..127 | h 0..127]
    int j = e & 7, lane = (e >> 3) & 63, kc = (e >> 9) & 7, ct = e >> 12;
    int row = ct * 16 + (lane & 15);
    int g = row / 112, c = row % 112;
    int q = (lane >> 4) & 3;
    float v = 0.0f;
    if (c < EE) {
      if (kc < 4) {
        int k = kc * 32 + q * 8 + j;
        v = lstm_wih[(g * EE + c) * HH + k];
      } else {
        int k = (kc - 4) * 32 + q * 8 + j;
        if (k < EE) v = lstm_whh[(g * EE + c) * EE + k];
      }
    }
    *(unsigned short*)(ws + OFF_LSTMW + (size_t)e * 2) = f2bf(v);
    return;
  }
  e -= 114688;
  if (e < 4096) {  // out_w (23x100 -> 32x128)
    int j = e & 7, lane = (e >> 3) & 63, kc = (e >> 9) & 3, ct = e >> 11;
    int n = ct * 16 + (lane & 15);
    int k = kc * 32 + ((lane >> 4) & 3) * 8 + j;
    float v = (n < VV && k < EE) ? out_w[n * EE + k] : 0.0f;
    *(unsigned short*)(ws + OFF_OUTW + (size_t)e * 2) = f2bf(v);
    return;
  }
  e -= 4096;
  if (e < 8192) {  // fc_z_w (128x64)
    int j = e & 7, lane = (e >> 3) & 63, kc = (e >> 9) & 1, ct = e >> 10;
    int n = ct * 16 + (lane & 15);
    int k = kc * 32 + ((lane >> 4) & 3) * 8 + j;
    *(unsigned short*)(ws + OFF_FCZW + (size_t)e * 2) = f2bf(fc_z_w[n * LL + k]);
    return;
  }
  e -= 8192;
  if (e < 448) {  // fused LSTM bias
    int g = e / 112, c = e % 112;
    float v = (c < EE) ? (lstm_bih[g * EE + c] + lstm_bhh[g * EE + c]) : 0.0f;
    *(float*)(ws + OFF_LBIAS + (size_t)e * 4) = v;
  }
}

// =====================================================================
// K1: GRU scan. 512 blocks x 512 thr (8 waves), 16 rows/block.
// h double-buffered in LDS in A-FRAG layout (conflict-free b128).
// Fast gate math (exp2+rcp), fast bf16 cvt, fma-form update.
// =====================================================================
__global__ __launch_bounds__(512, 4) void gru_kernel(
    const float* __restrict__ z, const int* __restrict__ x_in,
    const float* __restrict__ fc_z_b, const float* __restrict__ gru_bhh,
    char* __restrict__ ws)
{
  __shared__ unsigned short hfrag[2][2048];   // 4 kc frags of 1024B each
  __shared__ unsigned char idx_lds[TT * 16];
  const int tid  = threadIdx.x;
  const int wv   = tid >> 6;
  const int lane = tid & 63;
  const int l15  = lane & 15;
  const int q    = (lane >> 4) & 3;
  const int blk  = blockIdx.x;

  for (int i = tid; i < TT * 16; i += 512) {
    int t = i >> 4, r = i & 15;
    idx_lds[i] = (unsigned char)x_in[(blk * 16 + r) * TT + t];
  }

  // stationary weight fragments
  bf16x8 gw[3][4], tw[3];
#pragma unroll
  for (int g = 0; g < 3; g++) {
    int ct = g * 8 + wv;
#pragma unroll
    for (int kc = 0; kc < 4; kc++)
      gw[g][kc] = *(const bf16x8*)(ws + OFF_GRUW + (size_t)(ct * 4 + kc) * 1024 + lane * 16);
    tw[g] = *(const bf16x8*)(ws + OFF_TBL + (size_t)ct * 1024 + lane * 16);
  }
  const int col = wv * 16 + l15;
  const float b_r = gru_bhh[0 * HH + col];
  const float b_z = gru_bhh[1 * HH + col];
  const float b_n = gru_bhh[2 * HH + col];
  // A-frag write coords for this col: entry = wkc*512 + (wq*16+row)*8 + wj
  const int wbase = (col >> 5) * 512 + ((col >> 3) & 3) * 128 + (col & 7);

  // h0 = tanh(z @ fc_z_w^T + fc_z_b) via MFMA
  float h[4];
  {
    bf16x8 fw0 = *(const bf16x8*)(ws + OFF_FCZW + (size_t)(wv * 2 + 0) * 1024 + lane * 16);
    bf16x8 fw1 = *(const bf16x8*)(ws + OFF_FCZW + (size_t)(wv * 2 + 1) * 1024 + lane * 16);
    const float* zp = z + (size_t)(blk * 16 + l15) * LL + q * 8;
    f32x4 z0 = *(const f32x4*)(zp);
    f32x4 z1 = *(const f32x4*)(zp + 4);
    f32x4 z2 = *(const f32x4*)(zp + 32);
    f32x4 z3 = *(const f32x4*)(zp + 36);
    bf16x8 za0, za1;
#pragma unroll
    for (int j = 0; j < 4; j++) {
      za0[j]     = (short)f2bf(z0[j]);
      za0[4 + j] = (short)f2bf(z1[j]);
      za1[j]     = (short)f2bf(z2[j]);
      za1[4 + j] = (short)f2bf(z3[j]);
    }
    float fzb = fc_z_b[col];
    f32x4 acc = {fzb, fzb, fzb, fzb};
    acc = MFMA(za0, fw0, acc);
    acc = MFMA(za1, fw1, acc);
#pragma unroll
    for (int i = 0; i < 4; i++) {
      h[i] = tanh_(acc[i]);
      hfrag[0][wbase + (q * 4 + i) * 8] = f2bf_fast(h[i]);
    }
  }
  __syncthreads();

  int cur = 0;
  for (int t = 0; t < TT; t++) {
    // --- h-independent part first: bias init + one-hot table MFMAs ---
    int iv = idx_lds[t * 16 + l15];
    bf16x8 oh;
#pragma unroll
    for (int j = 0; j < 8; j++)
      oh[j] = (short)((iv == q * 8 + j) ? 0x3F80 : 0);

    f32x4 ar  = {b_r, b_r, b_r, b_r};
    f32x4 az  = {b_z, b_z, b_z, b_z};
    f32x4 ahn = {b_n, b_n, b_n, b_n};
    f32x4 axn = {0.0f, 0.0f, 0.0f, 0.0f};
    ar  = MFMA(oh, tw[0], ar);
    az  = MFMA(oh, tw[1], az);
    axn = MFMA(oh, tw[2], axn);

    // --- h-dependent part: conflict-free b128 A-frag reads ---
    bf16x8 a[4];
#pragma unroll
    for (int kc = 0; kc < 4; kc++)
      a[kc] = *(const bf16x8*)((const char*)hfrag[cur] + kc * 1024 + lane * 16);
#pragma unroll
    for (int kc = 0; kc < 4; kc++) {
      ar  = MFMA(a[kc], gw[0][kc], ar);
      az  = MFMA(a[kc], gw[1][kc], az);
      ahn = MFMA(a[kc], gw[2][kc], ahn);
    }

    int nb = cur ^ 1;
#pragma unroll
    for (int i = 0; i < 4; i++) {
      float r  = sigm(ar[i]);
      float zg = sigm(az[i]);
      float n  = tanh_(__builtin_fmaf(r, ahn[i], axn[i]));
      h[i] = __builtin_fmaf(zg, h[i] - n, n);   // (1-z)n + z h
      hfrag[nb][wbase + (q * 4 + i) * 8] = f2bf_fast(h[i]);
    }
    __syncthreads();
    // export y_t A-frags (already frag layout -> direct b128 copy)
    if (wv < 4) {
      bf16x8 yv = *(const bf16x8*)((const char*)hfrag[nb] + wv * 1024 + lane * 16);
      *(bf16x8*)(ws + OFF_Y + ((size_t)(blk * TT + t) * 4 + wv) * 1024 + lane * 16) = yv;
    }
    cur = nb;
  }
}

// =====================================================================
// K2: LSTM scan + logits, wave-specialized. 512 blocks x 960 thr
// (15 waves), 16 rows/block. Waves 0-6: y-projection -> P (LDS).
// Waves 7-13: recurrent; wave 14: logits (2 phases behind).
// Fast gate math (exp2+rcp), fast bf16 cvt.
// =====================================================================
__global__ __launch_bounds__(960) void lstm_kernel(
    const float* __restrict__ out_b, char* __restrict__ ws,
    float* __restrict__ out)
{
  __shared__ float Pbuf[2][4 * 7 * 64 * 4];       // 28 KB per buffer
  __shared__ unsigned short hbuf[2][2048];        // 4 KB per buffer (A-frags)
  const int tid  = threadIdx.x;
  const int wv   = tid >> 6;        // 0..14
  const int lane = tid & 63;
  const int l15  = lane & 15;
  const int q    = (lane >> 4) & 3;
  const int blk  = blockIdx.x;      // 0..511

  for (int i = tid; i < 4096; i += 960)
    ((unsigned short*)hbuf)[i] = 0;
  __syncthreads();

  if (wv < 7) {
    // ---------------- y-projection waves ----------------
    bf16x8 lwy[4][4];
#pragma unroll
    for (int g = 0; g < 4; g++)
#pragma unroll
      for (int kc = 0; kc < 4; kc++)
        lwy[g][kc] = *(const bf16x8*)(ws + OFF_LSTMW + (size_t)((g * 7 + wv) * 8 + kc) * 1024 + lane * 16);
    const int col = wv * 16 + l15;
    const float* lb = (const float*)(ws + OFF_LBIAS);
    float b[4];
#pragma unroll
    for (int g = 0; g < 4; g++) b[g] = lb[g * 112 + col];

    bf16x8 ya[4];
#pragma unroll
    for (int kc = 0; kc < 4; kc++)
      ya[kc] = *(const bf16x8*)(ws + OFF_Y + ((size_t)(blk * TT + 0) * 4 + kc) * 1024 + lane * 16);

    for (int p = 0; p < TT + 2; p++) {
      if (p <= TT - 1) {
#pragma unroll
        for (int g = 0; g < 4; g++) {
          f32x4 acc = {b[g], b[g], b[g], b[g]};
#pragma unroll
          for (int kc = 0; kc < 4; kc++)
            acc = MFMA(ya[kc], lwy[g][kc], acc);
          *(f32x4*)&Pbuf[p & 1][((g * 7 + wv) * 64 + lane) * 4] = acc;
        }
        if (p < TT - 1) {
#pragma unroll
          for (int kc = 0; kc < 4; kc++)
            ya[kc] = *(const bf16x8*)(ws + OFF_Y + ((size_t)(blk * TT + p + 1) * 4 + kc) * 1024 + lane * 16);
        }
      }
      __syncthreads();
    }
  } else if (wv < 14) {
    // ---------------- recurrent waves ----------------
    const int tile = wv - 7;
    bf16x8 lwh[4][4];
#pragma unroll
    for (int g = 0; g < 4; g++)
#pragma unroll
      for (int kc = 0; kc < 4; kc++)
        lwh[g][kc] = *(const bf16x8*)(ws + OFF_LSTMW + (size_t)((g * 7 + tile) * 8 + kc + 4) * 1024 + lane * 16);
    const int col = tile * 16 + l15;
    const int wbase = (col >> 5) * 512 + ((col >> 3) & 3) * 128 + (col & 7);
    float c[4] = {0, 0, 0, 0};

    for (int p = 0; p < TT + 2; p++) {
      if (p >= 1 && p <= TT) {
        const int rb = (p - 1) & 1;
        f32x4 ai = *(const f32x4*)&Pbuf[rb][((0 * 7 + tile) * 64 + lane) * 4];
        f32x4 af = *(const f32x4*)&Pbuf[rb][((1 * 7 + tile) * 64 + lane) * 4];
        f32x4 ag = *(const f32x4*)&Pbuf[rb][((2 * 7 + tile) * 64 + lane) * 4];
        f32x4 ao = *(const f32x4*)&Pbuf[rb][((3 * 7 + tile) * 64 + lane) * 4];
        bf16x8 ha[4];
#pragma unroll
        for (int kc = 0; kc < 4; kc++)
          ha[kc] = *(const bf16x8*)((const char*)hbuf[p & 1] + kc * 1024 + lane * 16);
#pragma unroll
        for (int kc = 0; kc < 4; kc++) {
          ai = MFMA(ha[kc], lwh[0][kc], ai);
          af = MFMA(ha[kc], lwh[1][kc], af);
          ag = MFMA(ha[kc], lwh[2][kc], ag);
          ao = MFMA(ha[kc], lwh[3][kc], ao);
        }
#pragma unroll
        for (int i = 0; i < 4; i++) {
          float ii = sigm(ai[i]), ff = sigm(af[i]);
          float gg = tanh_(ag[i]), oo = sigm(ao[i]);
          float cn = __builtin_fmaf(ff, c[i], ii * gg);
          c[i] = cn;
          hbuf[rb][wbase + (q * 4 + i) * 8] = f2bf_fast(oo * tanh_(cn));
        }
      }
      __syncthreads();
    }
  } else {
    // ---------------- logits wave ----------------
    bf16x8 ow[2][4];
#pragma unroll
    for (int ct = 0; ct < 2; ct++)
#pragma unroll
      for (int kc = 0; kc < 4; kc++)
        ow[ct][kc] = *(const bf16x8*)(ws + OFF_OUTW + (size_t)(ct * 4 + kc) * 1024 + lane * 16);
    float ob[2];
#pragma unroll
    for (int ct = 0; ct < 2; ct++) {
      int cv = ct * 16 + l15;
      ob[ct] = (cv < VV) ? out_b[cv] : 0.0f;
    }

    for (int p = 0; p < TT + 2; p++) {
      if (p >= 2) {
        const int t = p - 2;
        bf16x8 ha[4];
#pragma unroll
        for (int kc = 0; kc < 4; kc++)
          ha[kc] = *(const bf16x8*)((const char*)hbuf[p & 1] + kc * 1024 + lane * 16);
#pragma unroll
        for (int ct = 0; ct < 2; ct++) {
          f32x4 acc = {ob[ct], ob[ct], ob[ct], ob[ct]};
#pragma unroll
          for (int kc = 0; kc < 4; kc++)
            acc = MFMA(ha[kc], ow[ct][kc], acc);
          int cv = ct * 16 + l15;
          if (cv < VV) {
#pragma unroll
            for (int i = 0; i < 4; i++) {
              int rowg = blk * 16 + q * 4 + i;
              out[((size_t)rowg * TT + t) * VV + cv] = acc[i];
            }
          }
        }
      }
      __syncthreads();
    }
  }
}

extern "C" void kernel_launch(void* const* d_in, const int* in_sizes, int n_in,
                              void* d_out, int out_size, void* d_ws, size_t ws_size,
                              hipStream_t stream) {
  (void)in_sizes; (void)n_in; (void)out_size; (void)ws_size;
  const float* z        = (const float*)d_in[0];
  const int*   x_in     = (const int*)  d_in[1];
  const float* emb      = (const float*)d_in[2];
  const float* fc_z_w   = (const float*)d_in[3];
  const float* fc_z_b   = (const float*)d_in[4];
  const float* gru_wih  = (const float*)d_in[5];
  const float* gru_whh  = (const float*)d_in[6];
  const float* gru_bih  = (const float*)d_in[7];
  const float* gru_bhh  = (const float*)d_in[8];
  const float* lstm_wih = (const float*)d_in[9];
  const float* lstm_whh = (const float*)d_in[10];
  const float* lstm_bih = (const float*)d_in[11];
  const float* lstm_bhh = (const float*)d_in[12];
  const float* out_w    = (const float*)d_in[13];
  const float* out_b    = (const float*)d_in[14];
  char*  ws  = (char*)d_ws;
  float* out = (float*)d_out;

  prep_kernel<<<738, 256, 0, stream>>>(emb, fc_z_w, gru_wih, gru_whh, gru_bih,
                                       lstm_wih, lstm_whh, lstm_bih, lstm_bhh,
                                       out_w, ws);
  gru_kernel<<<512, 512, 0, stream>>>(z, x_in, fc_z_b, gru_bhh, ws);
  lstm_kernel<<<512, 960, 0, stream>>>(out_b, ws, out);
}